// Round 1
// 455.743 us; speedup vs baseline: 1.0332x; 1.0332x over previous
//
#include <hip/hip_runtime.h>
#include <hip/hip_bf16.h>

// Fused RNN: h_t = tanh([x_t, h_{t-1}] @ W_cell + b_cell), t = 0..127, then
// logits = h_final @ W_out + b_out.
// fp32 in/out; bf16 MFMA with fp32 accumulate. One block = 16 batch rows;
// W resident in VGPRs; h double-buffered in LDS (bf16).
// Key change vs prev: per-step sync is an lgkm-only fence + raw s_barrier, so
// the X prefetch (global->VGPR, no cross-wave visibility needed) stays in
// flight across steps instead of being drained by __syncthreads()'s vmcnt(0).
// Also: x/h accumulator chains split (ILP 4, depth <=5), per-step clamps
// dropped, h-writes packed to dwords via col = wid*32 + 2*l16 + nt mapping.

typedef __bf16 bf16x8 __attribute__((ext_vector_type(8)));
typedef float  f32x4  __attribute__((ext_vector_type(4)));
typedef float  f32x8  __attribute__((ext_vector_type(8)));
typedef unsigned short u16;

#define B_  4096
#define T_  128
#define D_  128
#define H_  150
#define O_  10

#define KX 4        // 128 / 32
#define KH 5        // 160 / 32 (padded)
#define HPAD 168    // row stride: 336 B, keeps ds_read_b128 16B-aligned

__global__ __launch_bounds__(320) void rnn_fused(
    const float* __restrict__ X,
    const float* __restrict__ Wc,
    const float* __restrict__ bc,
    const float* __restrict__ Wo,
    const float* __restrict__ bo,
    float* __restrict__ out)
{
    __shared__ __attribute__((aligned(16))) __bf16 sh_h[2][16][HPAD];

    const int tid  = threadIdx.x;
    const int wid  = tid >> 6;      // 0..4
    const int lane = tid & 63;
    const int q    = lane >> 4;     // 0..3
    const int l16  = lane & 15;
    const int row0 = blockIdx.x * 16;

    // ---- zero both h buffers ----
    {
        __bf16* p = &sh_h[0][0][0];
        for (int i = tid; i < 2 * 16 * HPAD; i += 320) p[i] = (__bf16)0.f;
    }

    // ---- preload W fragments (B-operand: B[k=q*8+i][n]) ----
    // Column mapping: col(nt, l16) = wid*32 + 2*l16 + nt  -> each lane's two
    // output columns are ADJACENT, so the epilogue writes one dword per row.
    bf16x8 wx[2][KX];
    bf16x8 wh[2][KH];
    float  bias[2];
    const int colw = wid * 32 + 2 * l16;          // 0..158 within padded 160
#pragma unroll
    for (int nt = 0; nt < 2; ++nt) {
        const int  j   = colw + nt;
        const bool jv  = (j < H_);
        const int  jcl = jv ? j : 0;
        bias[nt] = jv ? bc[jcl] : 0.f;
#pragma unroll
        for (int kt = 0; kt < KX; ++kt) {
            bf16x8 f;
#pragma unroll
            for (int i = 0; i < 8; ++i) {
                const int k = kt * 32 + q * 8 + i;               // < 128
                float v = Wc[k * H_ + jcl];
                v = fminf(fmaxf(v, -64.f), 64.f);                // one-time guard
                f[i] = jv ? (__bf16)v : (__bf16)0.f;
            }
            wx[nt][kt] = f;
        }
#pragma unroll
        for (int kt = 0; kt < KH; ++kt) {
            bf16x8 f;
#pragma unroll
            for (int i = 0; i < 8; ++i) {
                const int  kh  = kt * 32 + q * 8 + i;            // 0..159
                const bool kv  = jv && (kh < H_);
                const int  khc = (kh < H_) ? kh : 0;
                float v = Wc[(D_ + khc) * H_ + jcl];
                v = fminf(fmaxf(v, -64.f), 64.f);
                f[i] = kv ? (__bf16)v : (__bf16)0.f;
            }
            wh[nt][kt] = f;
        }
    }

    __syncthreads();

    // A-operand: lane holds A[m=l16][k = kt*32 + q*8 + i]
    const float* xrow = X + (size_t)(row0 + l16) * (T_ * D_) + q * 8;

    f32x8 xb0[KX], xb1[KX];
#pragma unroll
    for (int kt = 0; kt < KX; ++kt) xb0[kt] = *(const f32x8*)(xrow + 0 * D_ + kt * 32);
#pragma unroll
    for (int kt = 0; kt < KX; ++kt) xb1[kt] = *(const f32x8*)(xrow + 1 * D_ + kt * 32);

    auto step = [&](int t, f32x8 (&xb)[KX]) {
        // h fragments first: ds_read latency overlaps the cvt + x-MFMAs
        const __bf16 (*hb)[HPAD] = sh_h[t & 1];
        bf16x8 ah[KH];
#pragma unroll
        for (int kt = 0; kt < KH; ++kt)
            ah[kt] = *(const bf16x8*)(&hb[l16][kt * 32 + q * 8]);

        // convert X fragments fp32 -> bf16
        bf16x8 a[KX];
#pragma unroll
        for (int kt = 0; kt < KX; ++kt) {
#pragma unroll
            for (int i = 0; i < 8; ++i)
                a[kt][i] = (__bf16)xb[kt][i];
        }

        // prefetch X for t+2 into the just-consumed buffer; with the raw
        // barrier below these loads stay in flight across the next step.
        {
            int tt = t + 2; tt = (tt > T_ - 1) ? (T_ - 1) : tt;
#pragma unroll
            for (int kt = 0; kt < KX; ++kt)
                xb[kt] = *(const f32x8*)(xrow + (size_t)tt * D_ + kt * 32);
        }

        // split accumulators: x-chain (depth 4) and h-chain (depth 5), ILP 4
        f32x4 ax0 = {bias[0], bias[0], bias[0], bias[0]};
        f32x4 ax1 = {bias[1], bias[1], bias[1], bias[1]};
        f32x4 ah0 = {0.f, 0.f, 0.f, 0.f};
        f32x4 ah1 = {0.f, 0.f, 0.f, 0.f};
#pragma unroll
        for (int kt = 0; kt < KX; ++kt) {
            ax0 = __builtin_amdgcn_mfma_f32_16x16x32_bf16(a[kt], wx[0][kt], ax0, 0, 0, 0);
            ax1 = __builtin_amdgcn_mfma_f32_16x16x32_bf16(a[kt], wx[1][kt], ax1, 0, 0, 0);
        }
#pragma unroll
        for (int kt = 0; kt < KH; ++kt) {
            ah0 = __builtin_amdgcn_mfma_f32_16x16x32_bf16(ah[kt], wh[0][kt], ah0, 0, 0, 0);
            ah1 = __builtin_amdgcn_mfma_f32_16x16x32_bf16(ah[kt], wh[1][kt], ah1, 0, 0, 0);
        }

        // epilogue: tanh -> packed dword write (C layout: row=q*4+r, col pair)
        __bf16 (*ho)[HPAD] = sh_h[(t + 1) & 1];
#pragma unroll
        for (int r = 0; r < 4; ++r) {
            const float z0 = ax0[r] + ah0[r];
            const float z1 = ax1[r] + ah1[r];
            const float e0 = __builtin_amdgcn_exp2f(z0 * 2.8853900817779268f); // e^(2z)
            const float e1 = __builtin_amdgcn_exp2f(z1 * 2.8853900817779268f);
            const float h0 = 1.f - 2.f * __builtin_amdgcn_rcpf(e0 + 1.f);      // tanh
            const float h1 = 1.f - 2.f * __builtin_amdgcn_rcpf(e1 + 1.f);
            const unsigned p = (unsigned)__builtin_bit_cast(u16, (__bf16)h0)
                             | ((unsigned)__builtin_bit_cast(u16, (__bf16)h1) << 16);
            *(unsigned*)(&ho[q * 4 + r][colw]) = p;   // 4B-aligned, 2-way max
        }

        // lgkm-only fence + raw barrier: LDS writes made visible, but the
        // X prefetch (vmcnt, private VGPR dest) is NOT drained.
        asm volatile("s_waitcnt lgkmcnt(0)\n\ts_barrier" ::: "memory");
    };

    for (int t = 0; t < T_; t += 2) {
        step(t,     xb0);
        step(t + 1, xb1);
    }

    __syncthreads();

    // ---- classifier head: h_final lives in buffer (T_ & 1) == 0 ----
    if (tid < 16 * O_) {
        const int row = tid / O_;
        const int o   = tid - row * O_;
        float accv = bo[o];
        const __bf16* hf = &sh_h[0][row][0];
        for (int k = 0; k < H_; ++k)
            accv += (float)hf[k] * Wo[k * O_ + o];
        out[(size_t)(row0 + row) * O_ + o] = accv;
    }
}

extern "C" void kernel_launch(void* const* d_in, const int* in_sizes, int n_in,
                              void* d_out, int out_size, void* d_ws, size_t ws_size,
                              hipStream_t stream) {
    (void)in_sizes; (void)n_in; (void)out_size; (void)d_ws; (void)ws_size;
    const float* X  = (const float*)d_in[0];
    const float* Wc = (const float*)d_in[1];
    const float* bc = (const float*)d_in[2];
    const float* Wo = (const float*)d_in[3];
    const float* bo = (const float*)d_in[4];
    rnn_fused<<<dim3(B_ / 16), dim3(320), 0, stream>>>(X, Wc, bc, Wo, bo, (float*)d_out);
}